// Round 1
// baseline (58935.443 us; speedup 1.0000x reference)
//
#include <hip/hip_runtime.h>
#include <hip/hip_bf16.h>
#include <hip/hip_cooperative_groups.h>

namespace cg = cooperative_groups;

#define T_STEPS 512
#define B_SZ    128
#define I_SZ    256
#define H_SZ    256

// ---------- helpers ----------
__device__ __forceinline__ float load_xt(const float* p) { return *p; }
__device__ __forceinline__ float load_xt(const __hip_bfloat16* p) { return __bfloat162float(*p); }
__device__ __forceinline__ void store_xt(float* p, float v) { *p = v; }
__device__ __forceinline__ void store_xt(__hip_bfloat16* p, float v) { *p = __float2bfloat16(v); }

__device__ __forceinline__ float concrete_mask(float u) {
    const float EPS = 1e-7f;
    float logit_p = logf(0.25f + EPS) - logf(0.75f + EPS);
    float lu = logf(u + EPS) - logf(1.0f - u + EPS);
    float z = (logit_p + lu) * 10.0f;          // /TEMP (0.1)
    float sig = 1.0f / (1.0f + expf(-z));      // overflow-safe in fp32
    return (1.0f - sig) * (1.0f / 0.75f);      // /(1-P)
}

// ---------- kernel 1: masks + state init ----------
__global__ void mask_init_kernel(const float* __restrict__ ux, const float* __restrict__ uh,
                                 float* __restrict__ zx, float* __restrict__ zh,
                                 float* __restrict__ h_buf, float* __restrict__ c_buf) {
    int idx = blockIdx.x * blockDim.x + threadIdx.x;   // 0 .. 262143
    const int n = 4 * B_SZ * I_SZ;                     // 131072
    if (idx < n) {
        zx[idx] = concrete_mask(ux[idx]);
    } else {
        int j = idx - n;
        zh[j] = concrete_mask(uh[j]);
    }
    if (idx < B_SZ * H_SZ) { h_buf[idx] = 0.f; c_buf[idx] = 0.f; }
}

// ---------- kernel 2: x_pre GEMM (per-gate masked A @ W^T + Wb) ----------
// C[(t*B+b)][g][j] = sum_i input[t][b][i]*zx[g][b][i]*W[g][j][i] + Wb[g][j]
template <typename XT>
__global__ __launch_bounds__(256) void xpre_kernel(
        const float* __restrict__ input, const float* __restrict__ zx,
        const float* __restrict__ W, const float* __restrict__ Wb,
        XT* __restrict__ xpre) {
    __shared__ float As[16 * 68];
    __shared__ float Bs[16 * 68];
    const int tid = threadIdx.x;
    const int g    = blockIdx.z;
    const int row0 = blockIdx.x * 64;      // M = T*B = 65536
    const int col0 = blockIdx.y * 64;      // N = H = 256
    const int tx = tid & 15, ty = tid >> 4;
    float acc[4][4] = {};
    const float* Wg  = W  + (size_t)g * (H_SZ * I_SZ);
    const float* zxg = zx + (size_t)g * (B_SZ * I_SZ);
    for (int k0 = 0; k0 < I_SZ; k0 += 16) {
        #pragma unroll
        for (int p = 0; p < 4; ++p) {
            int li = p * 256 + tid;
            int m = li >> 4, kk = li & 15;
            int i = k0 + kk;
            int rowA = row0 + m;
            int bA = rowA & (B_SZ - 1);
            As[kk * 68 + m] = input[(size_t)rowA * I_SZ + i] * zxg[(size_t)bA * I_SZ + i];
            Bs[kk * 68 + m] = Wg[(size_t)(col0 + m) * I_SZ + i];
        }
        __syncthreads();
        #pragma unroll
        for (int kk = 0; kk < 16; ++kk) {
            float a[4], bb[4];
            #pragma unroll
            for (int q = 0; q < 4; ++q) a[q]  = As[kk * 68 + ty * 4 + q];
            #pragma unroll
            for (int q = 0; q < 4; ++q) bb[q] = Bs[kk * 68 + tx * 4 + q];
            #pragma unroll
            for (int x = 0; x < 4; ++x)
                #pragma unroll
                for (int y = 0; y < 4; ++y)
                    acc[x][y] += a[x] * bb[y];
        }
        __syncthreads();
    }
    #pragma unroll
    for (int x = 0; x < 4; ++x) {
        int row = row0 + ty * 4 + x;
        #pragma unroll
        for (int y = 0; y < 4; ++y) {
            int col = col0 + tx * 4 + y;
            float v = acc[x][y] + Wb[g * H_SZ + col];
            store_xt(xpre + (((size_t)row * 4 + g) * H_SZ + col), v);
        }
    }
}

// ---------- kernel 3: persistent recurrent scan (cooperative) ----------
// 512 blocks: btile(16) x jtile(32); block owns b in [btile*8,+8), j in [jtile*8,+8), all 4 gates.
// thread tid: g = tid>>6, bl = (tid>>3)&7, jl = tid&7  -> one s element per thread per step.
template <typename XT>
__global__ __launch_bounds__(256) void scan_kernel(
        const XT* __restrict__ xpre, const float* __restrict__ zh,
        const float* __restrict__ U, const float* __restrict__ Ub,
        float* __restrict__ h_buf, float* __restrict__ c_buf,
        float* __restrict__ out) {
    cg::grid_group grid = cg::this_grid();
    __shared__ float hm[32 * 260];   // [g*8+bl][k] padded rows (260 floats, 16B-aligned)
    __shared__ float st[256];        // s values: [g][bl][jl]

    const int tid   = threadIdx.x;
    const int btile = blockIdx.x >> 5;   // 0..15
    const int jtile = blockIdx.x & 31;   // 0..31
    const int g  = tid >> 6;
    const int bl = (tid >> 3) & 7;
    const int jl = tid & 7;
    const int b = btile * 8 + bl;
    const int j = jtile * 8 + jl;

    const float ub = Ub[g * H_SZ + j];
    const float4* U4 = (const float4*)(U + ((size_t)g * H_SZ + j) * H_SZ);

    for (int t = 0; t < T_STEPS; ++t) {
        // build hm tile: rows p=g*8+bl for this block's b range, k = tid (0..255)
        #pragma unroll 8
        for (int p = 0; p < 32; ++p) {
            int gg = p >> 3;
            int bb = btile * 8 + (p & 7);
            hm[p * 260 + tid] = h_buf[(size_t)bb * H_SZ + tid] *
                                zh[((size_t)gg * B_SZ + bb) * H_SZ + tid];
        }
        __syncthreads();

        float s = ub + load_xt(xpre + (((size_t)t * B_SZ + b) * 4 + g) * H_SZ + j);
        const float4* h4 = (const float4*)(hm + (g * 8 + bl) * 260);
        #pragma unroll 8
        for (int k = 0; k < H_SZ / 4; ++k) {
            float4 u = U4[k];
            float4 m = h4[k];
            s += m.x * u.x + m.y * u.y + m.z * u.z + m.w * u.w;
        }
        st[tid] = s;
        __syncthreads();

        if (tid < 64) {
            int bb = btile * 8 + (tid >> 3);
            int jj = jtile * 8 + (tid & 7);
            float si = st[tid];
            float sf = st[64 + tid];
            float so = st[128 + tid];
            float sg = st[192 + tid];
            float ig = 1.f / (1.f + expf(-si));
            float fg = 1.f / (1.f + expf(-sf));
            float og = 1.f / (1.f + expf(-so));
            float gv = tanhf(sg);
            size_t cidx = (size_t)bb * H_SZ + jj;
            float c = fg * c_buf[cidx] + ig * gv;
            c_buf[cidx] = c;
            float h = og * tanhf(c);
            h_buf[cidx] = h;
            out[(size_t)t * (B_SZ * H_SZ) + cidx] = h;
            if (t == T_STEPS - 1) {
                out[(size_t)T_STEPS * B_SZ * H_SZ + cidx] = h;
                out[(size_t)T_STEPS * B_SZ * H_SZ + B_SZ * H_SZ + cidx] = c;
            }
        }
        __threadfence();
        grid.sync();
    }
}

// ---------- launch ----------
extern "C" void kernel_launch(void* const* d_in, const int* in_sizes, int n_in,
                              void* d_out, int out_size, void* d_ws, size_t ws_size,
                              hipStream_t stream) {
    const float* input = (const float*)d_in[0];
    const float* ux    = (const float*)d_in[1];
    const float* uh    = (const float*)d_in[2];
    const float* W     = (const float*)d_in[3];
    const float* Wb    = (const float*)d_in[4];
    const float* U     = (const float*)d_in[5];
    const float* Ub    = (const float*)d_in[6];
    float* out = (float*)d_out;

    float* zx    = (float*)d_ws;           // 131072
    float* zh    = zx + 4 * B_SZ * I_SZ;   // 131072
    float* h_buf = zh + 4 * B_SZ * H_SZ;   // 32768
    float* c_buf = h_buf + B_SZ * H_SZ;    // 32768
    void*  xpre  = (void*)(c_buf + B_SZ * H_SZ);
    const size_t base_bytes = sizeof(float) * (size_t)(4 * B_SZ * I_SZ + 4 * B_SZ * H_SZ + 2 * B_SZ * H_SZ);
    const size_t xpre_elems = (size_t)T_STEPS * B_SZ * 4 * H_SZ;
    bool use_fp32 = (ws_size >= base_bytes + xpre_elems * sizeof(float));

    mask_init_kernel<<<dim3(1024), dim3(256), 0, stream>>>(ux, uh, zx, zh, h_buf, c_buf);

    dim3 gx(1024, 4, 4);   // (M/64, N/64, gates)
    if (use_fp32) {
        float* xp = (float*)xpre;
        xpre_kernel<float><<<gx, dim3(256), 0, stream>>>(input, zx, W, Wb, xp);
        void* args[] = { (void*)&xp, (void*)&zh, (void*)&U, (void*)&Ub,
                         (void*)&h_buf, (void*)&c_buf, (void*)&out };
        hipLaunchCooperativeKernel((const void*)scan_kernel<float>,
                                   dim3(512), dim3(256), args, 0u, stream);
    } else {
        __hip_bfloat16* xp = (__hip_bfloat16*)xpre;
        xpre_kernel<__hip_bfloat16><<<gx, dim3(256), 0, stream>>>(input, zx, W, Wb, xp);
        void* args[] = { (void*)&xp, (void*)&zh, (void*)&U, (void*)&Ub,
                         (void*)&h_buf, (void*)&c_buf, (void*)&out };
        hipLaunchCooperativeKernel((const void*)scan_kernel<__hip_bfloat16>,
                                   dim3(512), dim3(256), args, 0u, stream);
    }
}

// Round 2
// 15337.378 us; speedup vs baseline: 3.8426x; 3.8426x over previous
//
#include <hip/hip_runtime.h>
#include <hip/hip_bf16.h>

#define T_STEPS 512
#define B_SZ    128
#define I_SZ    256
#define H_SZ    256

// ---------- helpers ----------
__device__ __forceinline__ float concrete_mask(float u) {
    const float EPS = 1e-7f;
    float logit_p = logf(0.25f + EPS) - logf(0.75f + EPS);
    float lu = logf(u + EPS) - logf(1.0f - u + EPS);
    float z = (logit_p + lu) * 10.0f;          // /TEMP (0.1)
    float sig = 1.0f / (1.0f + expf(-z));
    return (1.0f - sig) * (1.0f / 0.75f);      // /(1-P)
}

// ---------- kernel 1: masks ----------
__global__ void mask_init_kernel(const float* __restrict__ ux, const float* __restrict__ uh,
                                 float* __restrict__ zx, float* __restrict__ zh) {
    int idx = blockIdx.x * blockDim.x + threadIdx.x;   // 0 .. 262143
    const int n = 4 * B_SZ * I_SZ;                     // 131072
    if (idx < n) zx[idx] = concrete_mask(ux[idx]);
    else         zh[idx - n] = concrete_mask(uh[idx - n]);
}

// ---------- kernel 2: x_pre GEMM (per-gate masked A @ W^T + Wb), bf16 out ----------
__global__ __launch_bounds__(256) void xpre_kernel(
        const float* __restrict__ input, const float* __restrict__ zx,
        const float* __restrict__ W, const float* __restrict__ Wb,
        __hip_bfloat16* __restrict__ xpre) {
    __shared__ float As[16 * 68];
    __shared__ float Bs[16 * 68];
    const int tid = threadIdx.x;
    const int g    = blockIdx.z;
    const int row0 = blockIdx.x * 64;      // M = T*B = 65536
    const int col0 = blockIdx.y * 64;      // N = H = 256
    const int tx = tid & 15, ty = tid >> 4;
    float acc[4][4] = {};
    const float* Wg  = W  + (size_t)g * (H_SZ * I_SZ);
    const float* zxg = zx + (size_t)g * (B_SZ * I_SZ);
    for (int k0 = 0; k0 < I_SZ; k0 += 16) {
        #pragma unroll
        for (int p = 0; p < 4; ++p) {
            int li = p * 256 + tid;
            int m = li >> 4, kk = li & 15;
            int i = k0 + kk;
            int rowA = row0 + m;
            int bA = rowA & (B_SZ - 1);
            As[kk * 68 + m] = input[(size_t)rowA * I_SZ + i] * zxg[(size_t)bA * I_SZ + i];
            Bs[kk * 68 + m] = Wg[(size_t)(col0 + m) * I_SZ + i];
        }
        __syncthreads();
        #pragma unroll
        for (int kk = 0; kk < 16; ++kk) {
            float a[4], bb[4];
            #pragma unroll
            for (int q = 0; q < 4; ++q) a[q]  = As[kk * 68 + ty * 4 + q];
            #pragma unroll
            for (int q = 0; q < 4; ++q) bb[q] = Bs[kk * 68 + tx * 4 + q];
            #pragma unroll
            for (int x = 0; x < 4; ++x)
                #pragma unroll
                for (int y = 0; y < 4; ++y)
                    acc[x][y] += a[x] * bb[y];
        }
        __syncthreads();
    }
    #pragma unroll
    for (int x = 0; x < 4; ++x) {
        int row = row0 + ty * 4 + x;
        #pragma unroll
        for (int y = 0; y < 4; ++y) {
            int col = col0 + tx * 4 + y;
            float v = acc[x][y] + Wb[g * H_SZ + col];
            xpre[((size_t)row * 4 + g) * H_SZ + col] = __float2bfloat16(v);
        }
    }
}

// ---------- kernel 3: independent per-batch-pair LSTM chains ----------
// Block bx owns batches {2bx, 2bx+1}. All state (h, c, masks, gate values) in LDS.
// Thread tid -> gate g = tid>>8, column k = tid&255. Each thread computes
// s[b][g][k] for both batches, sharing its U row (registers) across the pair.
// hm reads in the dot loop are wave-uniform LDS broadcasts (conflict-free).
__global__ __launch_bounds__(1024) void scan_chain_kernel(
        const __hip_bfloat16* __restrict__ xpre,  // [T][B][4][H]
        const float* __restrict__ zh,             // [4][B][H]
        const float* __restrict__ U,              // [4][H][H]
        const float* __restrict__ Ub,             // [4][H]
        float* __restrict__ out) {                // [T][B][H] ++ h_t ++ c_t
    __shared__ float zh_s[4][2][H_SZ];   // 8 KB
    __shared__ float hm_s[4][2][H_SZ];   // 8 KB
    __shared__ float st_s[2][4][H_SZ];   // 8 KB
    __shared__ float h_s[2][H_SZ];       // 2 KB
    __shared__ float c_s[2][H_SZ];       // 2 KB

    const int tid = threadIdx.x;
    const int b0  = blockIdx.x * 2;
    const int g   = tid >> 8;
    const int k   = tid & 255;

    // preload zh slice (2048 elems), init h/c/hm
    #pragma unroll
    for (int r = 0; r < 2; ++r) {
        int e = r * 1024 + tid;
        int gg = e >> 9, bb = (e >> 8) & 1, hh = e & 255;
        zh_s[gg][bb][hh] = zh[((size_t)gg * B_SZ + (b0 + bb)) * H_SZ + hh];
        ((float*)hm_s)[e] = 0.f;
    }
    if (tid < 512) { ((float*)h_s)[tid] = 0.f; ((float*)c_s)[tid] = 0.f; }
    __syncthreads();

    const float ubias = Ub[g * H_SZ + k];
    const float4* __restrict__ U4 = (const float4*)(U + ((size_t)g * H_SZ + k) * H_SZ);

    for (int t = 0; t < T_STEPS; ++t) {
        const __hip_bfloat16* xp = xpre + (((size_t)t * B_SZ + b0) * 4 + g) * H_SZ + k;
        float s0 = ubias + __bfloat162float(xp[0]);
        float s1 = ubias + __bfloat162float(xp[4 * H_SZ]);
        const float4* m0 = (const float4*)hm_s[g][0];
        const float4* m1 = (const float4*)hm_s[g][1];
        #pragma unroll 8
        for (int hh = 0; hh < H_SZ / 4; ++hh) {
            float4 u = U4[hh];
            float4 a = m0[hh];
            float4 b = m1[hh];
            s0 += u.x * a.x + u.y * a.y + u.z * a.z + u.w * a.w;
            s1 += u.x * b.x + u.y * b.y + u.z * b.z + u.w * b.w;
        }
        st_s[0][g][k] = s0;
        st_s[1][g][k] = s1;
        __syncthreads();

        if (tid < 512) {
            int bb = tid >> 8, kk = tid & 255;
            float si = st_s[bb][0][kk];
            float sf = st_s[bb][1][kk];
            float so = st_s[bb][2][kk];
            float sg = st_s[bb][3][kk];
            float ig = 1.f / (1.f + expf(-si));
            float fg = 1.f / (1.f + expf(-sf));
            float og = 1.f / (1.f + expf(-so));
            float gv = tanhf(sg);
            float c = fg * c_s[bb][kk] + ig * gv;
            c_s[bb][kk] = c;
            float h = og * tanhf(c);
            h_s[bb][kk] = h;
            out[((size_t)t * B_SZ + (b0 + bb)) * H_SZ + kk] = h;
            if (t == T_STEPS - 1) {
                size_t tail = (size_t)T_STEPS * B_SZ * H_SZ;
                out[tail + (size_t)(b0 + bb) * H_SZ + kk] = h;
                out[tail + (size_t)B_SZ * H_SZ + (size_t)(b0 + bb) * H_SZ + kk] = c;
            }
        }
        __syncthreads();

        // rebuild hm = h * zh for next step (2 elems/thread)
        #pragma unroll
        for (int r = 0; r < 2; ++r) {
            int e = r * 1024 + tid;
            int gg = e >> 9, bb = (e >> 8) & 1, hh = e & 255;
            hm_s[gg][bb][hh] = h_s[bb][hh] * zh_s[gg][bb][hh];
        }
        __syncthreads();
    }
}

// ---------- launch ----------
extern "C" void kernel_launch(void* const* d_in, const int* in_sizes, int n_in,
                              void* d_out, int out_size, void* d_ws, size_t ws_size,
                              hipStream_t stream) {
    const float* input = (const float*)d_in[0];
    const float* ux    = (const float*)d_in[1];
    const float* uh    = (const float*)d_in[2];
    const float* W     = (const float*)d_in[3];
    const float* Wb    = (const float*)d_in[4];
    const float* U     = (const float*)d_in[5];
    const float* Ub    = (const float*)d_in[6];
    float* out = (float*)d_out;

    float* zx = (float*)d_ws;                              // 4*B*I
    float* zh = zx + 4 * B_SZ * I_SZ;                      // 4*B*H
    __hip_bfloat16* xpre = (__hip_bfloat16*)(zh + 4 * B_SZ * H_SZ);

    mask_init_kernel<<<dim3(1024), dim3(256), 0, stream>>>(ux, uh, zx, zh);

    dim3 gx(1024, 4, 4);   // (M/64, N/64, gates)
    xpre_kernel<<<gx, dim3(256), 0, stream>>>(input, zx, W, Wb, xpre);

    scan_chain_kernel<<<dim3(B_SZ / 2), dim3(1024), 0, stream>>>(xpre, zh, U, Ub, out);
}

// Round 3
// 5577.197 us; speedup vs baseline: 10.5672x; 2.7500x over previous
//
#include <hip/hip_runtime.h>
#include <hip/hip_bf16.h>

#define T_STEPS 512
#define B_SZ    128
#define I_SZ    256
#define H_SZ    256
#define NB      16                 // batches per scan block
#define SCAN_BLOCKS (B_SZ / NB)    // 8
#define SCAN_THREADS 512

typedef __attribute__((ext_vector_type(8))) short short8;
typedef __attribute__((ext_vector_type(4))) float floatx4;
union I4S8 { uint4 u; short8 s; };

// LDS layout (dynamic): hm frags [g][kk] chunks of 1KB, stride 1040B (bank-spread)
#define HM_G_STRIDE 8320            // 8 * 1040
#define ST_OFF      33280           // 4 * 8320
#define ST_ROW      268             // fp32 row stride (256 + 12 pad; 16B-aligned, 2-way banks)
#define SMEM_BYTES  (ST_OFF + 64 * ST_ROW * 4)   // 33280 + 68608 = 101888

__device__ __forceinline__ float fast_sigmoid(float x) {
    return 1.f / (1.f + __expf(-x));
}
__device__ __forceinline__ float fast_tanh(float x) {
    float ax = fabsf(x);
    float e = __expf(-2.f * ax);
    float t = (1.f - e) / (1.f + e);
    return copysignf(t, x);
}
__device__ __forceinline__ ushort f2bf(float v) {
    __hip_bfloat16 hb = __float2bfloat16(v);
    return *(ushort*)&hb;
}
__device__ __forceinline__ float bf2f(ushort u) {
    unsigned int b = ((unsigned int)u) << 16;
    return __uint_as_float(b);
}

__device__ __forceinline__ float concrete_mask(float u) {
    const float EPS = 1e-7f;
    float logit_p = logf(0.25f + EPS) - logf(0.75f + EPS);
    float lu = logf(u + EPS) - logf(1.0f - u + EPS);
    float z = (logit_p + lu) * 10.0f;
    float sig = 1.0f / (1.0f + expf(-z));
    return (1.0f - sig) * (1.0f / 0.75f);
}

// ---------- kernel 1: masks (zx fp32 for xpre GEMM, zh bf16 for scan) ----------
__global__ void mask_kernel(const float* __restrict__ ux, const float* __restrict__ uh,
                            float* __restrict__ zx, __hip_bfloat16* __restrict__ zh) {
    int idx = blockIdx.x * blockDim.x + threadIdx.x;   // 0 .. 262143
    const int n = 4 * B_SZ * I_SZ;                     // 131072
    if (idx < n) zx[idx] = concrete_mask(ux[idx]);
    else         zh[idx - n] = __float2bfloat16(concrete_mask(uh[idx - n]));
}

// ---------- kernel 2: swizzle U into MFMA B-fragment order, bf16 ----------
// frag (g, ktile, kk): lane l holds B[k=kk*32+((l>>4)&3)*8+j][n=ktile*16+(l&15)],
// B[k][n] = U[g][n][k]. Stored as uint4 per lane: U_sw uint4 index = ((g*16+ktile)*8+kk)*64+lane.
__global__ void uswz_kernel(const float* __restrict__ U, __hip_bfloat16* __restrict__ U_sw) {
    int tId = blockIdx.x * 256 + threadIdx.x;    // 0 .. 32767
    int lane  = tId & 63;
    int kk    = (tId >> 6) & 7;
    int ktile = (tId >> 9) & 15;
    int g     = tId >> 13;
    int nCol  = ktile * 16 + (lane & 15);
    int h0    = kk * 32 + ((lane >> 4) & 3) * 8;
    const float* src = U + ((size_t)g * H_SZ + nCol) * H_SZ + h0;
    ushort o[8];
    #pragma unroll
    for (int j = 0; j < 8; ++j) o[j] = f2bf(src[j]);
    uint4 pk;
    pk.x = (uint)o[0] | ((uint)o[1] << 16);
    pk.y = (uint)o[2] | ((uint)o[3] << 16);
    pk.z = (uint)o[4] | ((uint)o[5] << 16);
    pk.w = (uint)o[6] | ((uint)o[7] << 16);
    ((uint4*)U_sw)[tId] = pk;
}

// ---------- kernel 3: x_pre GEMM (masked A @ W^T + Wb + Ub), bf16 out ----------
__global__ __launch_bounds__(256) void xpre_kernel(
        const float* __restrict__ input, const float* __restrict__ zx,
        const float* __restrict__ W, const float* __restrict__ Wb,
        const float* __restrict__ Ub, __hip_bfloat16* __restrict__ xpre) {
    __shared__ float As[16 * 68];
    __shared__ float Bs[16 * 68];
    const int tid = threadIdx.x;
    const int g    = blockIdx.z;
    const int row0 = blockIdx.x * 64;      // M = T*B = 65536
    const int col0 = blockIdx.y * 64;      // N = H = 256
    const int tx = tid & 15, ty = tid >> 4;
    float acc[4][4] = {};
    const float* Wg  = W  + (size_t)g * (H_SZ * I_SZ);
    const float* zxg = zx + (size_t)g * (B_SZ * I_SZ);
    for (int k0 = 0; k0 < I_SZ; k0 += 16) {
        #pragma unroll
        for (int p = 0; p < 4; ++p) {
            int li = p * 256 + tid;
            int m = li >> 4, kk = li & 15;
            int i = k0 + kk;
            int rowA = row0 + m;
            int bA = rowA & (B_SZ - 1);
            As[kk * 68 + m] = input[(size_t)rowA * I_SZ + i] * zxg[(size_t)bA * I_SZ + i];
            Bs[kk * 68 + m] = Wg[(size_t)(col0 + m) * I_SZ + i];
        }
        __syncthreads();
        #pragma unroll
        for (int kk = 0; kk < 16; ++kk) {
            float a[4], bb[4];
            #pragma unroll
            for (int q = 0; q < 4; ++q) a[q]  = As[kk * 68 + ty * 4 + q];
            #pragma unroll
            for (int q = 0; q < 4; ++q) bb[q] = Bs[kk * 68 + tx * 4 + q];
            #pragma unroll
            for (int x = 0; x < 4; ++x)
                #pragma unroll
                for (int y = 0; y < 4; ++y)
                    acc[x][y] += a[x] * bb[y];
        }
        __syncthreads();
    }
    #pragma unroll
    for (int x = 0; x < 4; ++x) {
        int row = row0 + ty * 4 + x;
        #pragma unroll
        for (int y = 0; y < 4; ++y) {
            int col = col0 + tx * 4 + y;
            float v = acc[x][y] + Wb[g * H_SZ + col] + Ub[g * H_SZ + col];
            xpre[((size_t)row * 4 + g) * H_SZ + col] = __float2bfloat16(v);
        }
    }
}

// ---------- kernel 4: MFMA scan ----------
// 8 blocks x 512 threads. Block owns batches [b0, b0+16). Wave w: gate g=w>>1,
// k-half = w&1 -> 8 n-tiles x 8 K-chunks of mfma_f32_16x16x32_bf16 per step.
// A (hm = h*zh, bf16) staged in LDS in A-frag layout; B (U) streamed from L2 in
// swizzled frag order, register double-buffered. s exchanged via LDS; gates,
// c/h update, hm rebuild in epilogue (all 512 threads, 8 k each).
__global__ __launch_bounds__(SCAN_THREADS, 2) void scan_mfma_kernel(
        const __hip_bfloat16* __restrict__ xpre,   // [T][B][4][H], includes Wb+Ub
        const __hip_bfloat16* __restrict__ zh,     // [4][B][H] bf16
        const __hip_bfloat16* __restrict__ U_sw,   // swizzled B-frags
        float* __restrict__ out) {
    extern __shared__ __align__(16) char smem[];
    const int tid  = threadIdx.x;
    const int b0   = blockIdx.x * NB;
    // MFMA mapping
    const int w     = tid >> 6;
    const int lane  = tid & 63;
    const int g_w   = w >> 1;
    const int khalf = w & 1;
    // epilogue mapping
    const int be      = tid >> 5;             // 0..15 (batch)
    const int k8      = (tid & 31) * 8;       // 0..248
    const int kk_e    = k8 >> 5;
    const int lane_hm = (be & 15) | (((k8 >> 3) & 3) << 4);

    // persistent epilogue registers
    uint4 zhreg[4], xp[4];
    float c8[8], h8[8];
    #pragma unroll
    for (int g = 0; g < 4; ++g) {
        zhreg[g] = *(const uint4*)(zh + ((size_t)g * B_SZ + (b0 + be)) * H_SZ + k8);
        xp[g]    = *(const uint4*)(xpre + ((size_t)(b0 + be) * 4 + g) * H_SZ + k8);
    }
    #pragma unroll
    for (int j = 0; j < 8; ++j) c8[j] = 0.f;

    // zero hm frags (h0 = 0)
    for (int i = tid; i < ST_OFF / 16; i += SCAN_THREADS)
        ((uint4*)smem)[i] = make_uint4(0u, 0u, 0u, 0u);
    __syncthreads();

    const uint4* Uw = (const uint4*)U_sw + ((size_t)(g_w * 16 + khalf * 8) * 8) * 64 + lane;
    float* st = (float*)(smem + ST_OFF);

    for (int t = 0; t < T_STEPS; ++t) {
        // ---- MFMA phase: s_partial = hm @ U^T ----
        I4S8 afr[8];
        #pragma unroll
        for (int kk = 0; kk < 8; ++kk)
            afr[kk].u = *(const uint4*)(smem + g_w * HM_G_STRIDE + kk * 1040 + lane * 16);

        floatx4 acc[8];
        uint4 bbuf[2][8];
        #pragma unroll
        for (int kk = 0; kk < 8; ++kk) bbuf[0][kk] = Uw[kk * 64];
        #pragma unroll
        for (int nt = 0; nt < 8; ++nt) {
            #pragma unroll
            for (int r = 0; r < 4; ++r) acc[nt][r] = 0.f;
            if (nt < 7) {
                #pragma unroll
                for (int kk = 0; kk < 8; ++kk)
                    bbuf[(nt + 1) & 1][kk] = Uw[((nt + 1) * 8 + kk) * 64];
            }
            #pragma unroll
            for (int kk = 0; kk < 8; ++kk) {
                I4S8 bb; bb.u = bbuf[nt & 1][kk];
                acc[nt] = __builtin_amdgcn_mfma_f32_16x16x32_bf16(afr[kk].s, bb.s, acc[nt], 0, 0, 0);
            }
        }
        // C -> st LDS  (row (b*4+g)*ST_ROW + k)
        #pragma unroll
        for (int nt = 0; nt < 8; ++nt) {
            int kcol  = khalf * 128 + nt * 16 + (lane & 15);
            int brow4 = (lane >> 4) * 4;
            #pragma unroll
            for (int r = 0; r < 4; ++r)
                st[((brow4 + r) * 4 + g_w) * ST_ROW + kcol] = acc[nt][r];
        }
        __syncthreads();

        // ---- epilogue: gates, c/h update, hm rebuild ----
        float sg[4][8];
        #pragma unroll
        for (int g = 0; g < 4; ++g) {
            const float* strow = st + ((be * 4 + g) * ST_ROW + k8);
            float4 lo = *(const float4*)(strow);
            float4 hi = *(const float4*)(strow + 4);
            sg[g][0] = lo.x; sg[g][1] = lo.y; sg[g][2] = lo.z; sg[g][3] = lo.w;
            sg[g][4] = hi.x; sg[g][5] = hi.y; sg[g][6] = hi.z; sg[g][7] = hi.w;
            const ushort* xs = (const ushort*)&xp[g];
            #pragma unroll
            for (int j = 0; j < 8; ++j) sg[g][j] += bf2f(xs[j]);
        }
        #pragma unroll
        for (int j = 0; j < 8; ++j) {
            float iv = fast_sigmoid(sg[0][j]);
            float fv = fast_sigmoid(sg[1][j]);
            float ov = fast_sigmoid(sg[2][j]);
            float gv = fast_tanh(sg[3][j]);
            float c  = fv * c8[j] + iv * gv;
            c8[j] = c;
            h8[j] = ov * fast_tanh(c);
        }
        // out[t]
        {
            float* op = out + ((size_t)t * B_SZ + (b0 + be)) * H_SZ + k8;
            *(float4*)(op)     = make_float4(h8[0], h8[1], h8[2], h8[3]);
            *(float4*)(op + 4) = make_float4(h8[4], h8[5], h8[6], h8[7]);
        }
        // hm = h * zh -> LDS A-frag layout
        #pragma unroll
        for (int g = 0; g < 4; ++g) {
            const ushort* zs = (const ushort*)&zhreg[g];
            uint4 pk;
            uint v0 = (uint)f2bf(h8[0] * bf2f(zs[0])) | ((uint)f2bf(h8[1] * bf2f(zs[1])) << 16);
            uint v1 = (uint)f2bf(h8[2] * bf2f(zs[2])) | ((uint)f2bf(h8[3] * bf2f(zs[3])) << 16);
            uint v2 = (uint)f2bf(h8[4] * bf2f(zs[4])) | ((uint)f2bf(h8[5] * bf2f(zs[5])) << 16);
            uint v3 = (uint)f2bf(h8[6] * bf2f(zs[6])) | ((uint)f2bf(h8[7] * bf2f(zs[7])) << 16);
            pk.x = v0; pk.y = v1; pk.z = v2; pk.w = v3;
            *(uint4*)(smem + g * HM_G_STRIDE + kk_e * 1040 + lane_hm * 16) = pk;
        }
        // prefetch xpre for t+1 (in flight through next MFMA phase)
        {
            int tn = (t + 1 < T_STEPS) ? t + 1 : t;
            #pragma unroll
            for (int g = 0; g < 4; ++g)
                xp[g] = *(const uint4*)(xpre + (((size_t)tn * B_SZ + (b0 + be)) * 4 + g) * H_SZ + k8);
        }
        if (t == T_STEPS - 1) {
            size_t tail = (size_t)T_STEPS * B_SZ * H_SZ;
            float* hp = out + tail + (size_t)(b0 + be) * H_SZ + k8;
            float* cp = hp + (size_t)B_SZ * H_SZ;
            *(float4*)(hp)     = make_float4(h8[0], h8[1], h8[2], h8[3]);
            *(float4*)(hp + 4) = make_float4(h8[4], h8[5], h8[6], h8[7]);
            *(float4*)(cp)     = make_float4(c8[0], c8[1], c8[2], c8[3]);
            *(float4*)(cp + 4) = make_float4(c8[4], c8[5], c8[6], c8[7]);
        }
        __syncthreads();
    }
}

// ---------- launch ----------
extern "C" void kernel_launch(void* const* d_in, const int* in_sizes, int n_in,
                              void* d_out, int out_size, void* d_ws, size_t ws_size,
                              hipStream_t stream) {
    const float* input = (const float*)d_in[0];
    const float* ux    = (const float*)d_in[1];
    const float* uh    = (const float*)d_in[2];
    const float* W     = (const float*)d_in[3];
    const float* Wb    = (const float*)d_in[4];
    const float* U     = (const float*)d_in[5];
    const float* Ub    = (const float*)d_in[6];
    float* out = (float*)d_out;

    // workspace layout (all 16B aligned)
    float* zx            = (float*)d_ws;                                   // 131072 f32
    __hip_bfloat16* zh   = (__hip_bfloat16*)(zx + 4 * B_SZ * I_SZ);        // 131072 bf16
    __hip_bfloat16* U_sw = zh + 4 * B_SZ * H_SZ;                           // 262144 bf16
    __hip_bfloat16* xpre = U_sw + 4 * H_SZ * H_SZ;                         // T*B*4*H bf16

    mask_kernel<<<dim3(1024), dim3(256), 0, stream>>>(ux, uh, zx, zh);
    uswz_kernel<<<dim3(128), dim3(256), 0, stream>>>(U, U_sw);

    dim3 gx(1024, 4, 4);   // (M/64, N/64, gates)
    xpre_kernel<<<gx, dim3(256), 0, stream>>>(input, zx, W, Wb, Ub, xpre);

    scan_mfma_kernel<<<dim3(SCAN_BLOCKS), dim3(SCAN_THREADS), SMEM_BYTES, stream>>>(
        xpre, zh, U_sw, out);
}

// Round 4
// 4316.431 us; speedup vs baseline: 13.6537x; 1.2921x over previous
//
#include <hip/hip_runtime.h>
#include <hip/hip_bf16.h>

#define T_STEPS 512
#define B_SZ    128
#define I_SZ    256
#define H_SZ    256
#define NB      16                 // batches per scan block
#define SCAN_BLOCKS (B_SZ / NB)    // 8
#define SCAN_THREADS 512

typedef __attribute__((ext_vector_type(8))) short short8;
typedef __attribute__((ext_vector_type(4))) float floatx4;
union I4S8 { uint4 u; short8 s; };

// ---- scan LDS layout ----
#define HM_G_STRIDE 8320                 // hm: g*8320 + kk*1040 + lane*16   (33280 B)
#define ST_OFF      33280
#define ST_ROW      268                  // fp32 row stride (b*4+g rows, 64 rows)
#define ULDS_OFF    (ST_OFF + 64 * ST_ROW * 4)        // 33280 + 68608 = 101888
#define ULDS_W      7168                 // 7 frags * 1024 per wave
#define SMEM_BYTES  (ULDS_OFF + 8 * ULDS_W)           // 159232  (< 160 KiB)

// ---- U-frag tiering per wave (64 frags = nt(8) x kk(8)) ----
// kk 0..3           : register-resident (32 frags)
// kk == 4, nt 0..6  : LDS (7 frags, index nt)
// rest (25 frags)   : streamed, 4-deep rotating pipeline
// consumption order: pairs p=(nt 2p,2p+1), kk ascending, e=0,1
static constexpr int SORD[8][8] = {
    {-1,-1,-1,-1,-1, 0, 2, 4},
    {-1,-1,-1,-1,-1, 1, 3, 5},
    {-1,-1,-1,-1,-1, 6, 8,10},
    {-1,-1,-1,-1,-1, 7, 9,11},
    {-1,-1,-1,-1,-1,12,14,16},
    {-1,-1,-1,-1,-1,13,15,17},
    {-1,-1,-1,-1,-1,19,21,23},
    {-1,-1,-1,-1,18,20,22,24},
};
static constexpr int SFRG[25] = {  // ordinal -> frag linear index nt*8+kk
     5,13, 6,14, 7,15,
    21,29,22,30,23,31,
    37,45,38,46,39,47,
    60,53,61,54,62,55,63
};

__device__ __forceinline__ float fast_sigmoid(float x) {
    return 1.f / (1.f + __expf(-x));
}
__device__ __forceinline__ float fast_tanh(float x) {
    float ax = fabsf(x);
    float e = __expf(-2.f * ax);
    float t = (1.f - e) / (1.f + e);
    return copysignf(t, x);
}
__device__ __forceinline__ ushort f2bf(float v) {
    __hip_bfloat16 hb = __float2bfloat16(v);
    return *(ushort*)&hb;
}
__device__ __forceinline__ float bf2f(ushort u) {
    unsigned int b = ((unsigned int)u) << 16;
    return __uint_as_float(b);
}
__device__ __forceinline__ float concrete_mask(float u) {
    const float EPS = 1e-7f;
    float logit_p = logf(0.25f + EPS) - logf(0.75f + EPS);
    float lu = logf(u + EPS) - logf(1.0f - u + EPS);
    float z = (logit_p + lu) * 10.0f;
    float sig = 1.0f / (1.0f + expf(-z));
    return (1.0f - sig) * (1.0f / 0.75f);
}

// ---------- kernel 1: masks (zx fp32, zh bf16) ----------
__global__ void mask_kernel(const float* __restrict__ ux, const float* __restrict__ uh,
                            float* __restrict__ zx, __hip_bfloat16* __restrict__ zh) {
    int idx = blockIdx.x * blockDim.x + threadIdx.x;   // 0 .. 262143
    const int n = 4 * B_SZ * I_SZ;
    if (idx < n) zx[idx] = concrete_mask(ux[idx]);
    else         zh[idx - n] = __float2bfloat16(concrete_mask(uh[idx - n]));
}

// ---------- kernel 2: swizzle a [4][256][256] fp32 matrix into MFMA B-frag bf16 ----------
// frag (g, ktile, kk): lane l holds B[k=kk*32+((l>>4)&3)*8+j][n=ktile*16+(l&15)],
// B[k][n] = M[g][n][k].  uint4 index = ((g*16+ktile)*8+kk)*64+lane.
__global__ void uswz_kernel(const float* __restrict__ M, __hip_bfloat16* __restrict__ M_sw) {
    int tId = blockIdx.x * 256 + threadIdx.x;    // 0 .. 32767
    int lane  = tId & 63;
    int kk    = (tId >> 6) & 7;
    int ktile = (tId >> 9) & 15;
    int g     = tId >> 13;
    int nCol  = ktile * 16 + (lane & 15);
    int h0    = kk * 32 + ((lane >> 4) & 3) * 8;
    const float* src = M + ((size_t)g * 256 + nCol) * 256 + h0;
    ushort o[8];
    #pragma unroll
    for (int j = 0; j < 8; ++j) o[j] = f2bf(src[j]);
    uint4 pk;
    pk.x = (uint)o[0] | ((uint)o[1] << 16);
    pk.y = (uint)o[2] | ((uint)o[3] << 16);
    pk.z = (uint)o[4] | ((uint)o[5] << 16);
    pk.w = (uint)o[6] | ((uint)o[7] << 16);
    ((uint4*)M_sw)[tId] = pk;
}

// ---------- kernel 3: x_pre via MFMA (masked input @ W^T + Wb + Ub), bf16 out ----------
// 1024 blocks x 512 thr; block: 64 M-rows x 256 N. Wave (g, khalf): 4 mtiles x 8 ntiles.
__global__ __launch_bounds__(512, 2) void xpre_mfma_kernel(
        const float* __restrict__ input, const float* __restrict__ zx,
        const __hip_bfloat16* __restrict__ W_sw,
        const float* __restrict__ Wb, const float* __restrict__ Ub,
        __hip_bfloat16* __restrict__ xpre) {
    const int tid   = threadIdx.x;
    const int w     = tid >> 6;
    const int lane  = tid & 63;
    const int g     = w >> 1;
    const int khalf = w & 1;
    const int row0  = blockIdx.x * 64;
    const int mrow  = lane & 15;
    const int kq    = lane >> 4;     // 0..3

    floatx4 acc[4][8];
    #pragma unroll
    for (int mt = 0; mt < 4; ++mt)
        #pragma unroll
        for (int nt = 0; nt < 8; ++nt)
            #pragma unroll
            for (int r = 0; r < 4; ++r) acc[mt][nt][r] = 0.f;

    const uint4* Wp = (const uint4*)W_sw + ((size_t)((g * 16 + khalf * 8) * 8)) * 64 + lane;

    for (int kc = 0; kc < 8; ++kc) {
        I4S8 af[4];
        const int i0 = kc * 32 + kq * 8;
        #pragma unroll
        for (int mt = 0; mt < 4; ++mt) {
            int row = row0 + mt * 16 + mrow;
            int b   = row & (B_SZ - 1);
            const float4* ip = (const float4*)(input + (size_t)row * I_SZ + i0);
            const float4* zp = (const float4*)(zx + ((size_t)g * B_SZ + b) * I_SZ + i0);
            float4 a0 = ip[0], a1 = ip[1];
            float4 z0 = zp[0], z1 = zp[1];
            uint4 pk;
            pk.x = (uint)f2bf(a0.x * z0.x) | ((uint)f2bf(a0.y * z0.y) << 16);
            pk.y = (uint)f2bf(a0.z * z0.z) | ((uint)f2bf(a0.w * z0.w) << 16);
            pk.z = (uint)f2bf(a1.x * z1.x) | ((uint)f2bf(a1.y * z1.y) << 16);
            pk.w = (uint)f2bf(a1.z * z1.z) | ((uint)f2bf(a1.w * z1.w) << 16);
            af[mt].u = pk;
        }
        #pragma unroll
        for (int nt = 0; nt < 8; ++nt) {
            I4S8 bb; bb.u = Wp[(nt * 8 + kc) * 64];
            #pragma unroll
            for (int mt = 0; mt < 4; ++mt)
                acc[mt][nt] = __builtin_amdgcn_mfma_f32_16x16x32_bf16(af[mt].s, bb.s, acc[mt][nt], 0, 0, 0);
        }
    }
    // epilogue: + Wb + Ub, store bf16 (C layout: row=(lane>>4)*4+r, col=lane&15)
    #pragma unroll
    for (int nt = 0; nt < 8; ++nt) {
        int col = khalf * 128 + nt * 16 + (lane & 15);
        float bias = Wb[g * H_SZ + col] + Ub[g * H_SZ + col];
        #pragma unroll
        for (int mt = 0; mt < 4; ++mt) {
            #pragma unroll
            for (int r = 0; r < 4; ++r) {
                int row = row0 + mt * 16 + (lane >> 4) * 4 + r;
                xpre[((size_t)row * 4 + g) * H_SZ + col] = __float2bfloat16(acc[mt][nt][r] + bias);
            }
        }
    }
}

// ---------- kernel 4: MFMA scan with tiered-resident U ----------
__global__ __launch_bounds__(SCAN_THREADS, 2) void scan_mfma_kernel(
        const __hip_bfloat16* __restrict__ xpre,   // [T][B][4][H], includes Wb+Ub
        const __hip_bfloat16* __restrict__ zh,     // [4][B][H] bf16
        const __hip_bfloat16* __restrict__ U_sw,   // swizzled B-frags
        float* __restrict__ out) {
    extern __shared__ __align__(16) char smem[];
    const int tid  = threadIdx.x;
    const int b0   = blockIdx.x * NB;
    const int w     = tid >> 6;
    const int lane  = tid & 63;
    const int g_w   = w >> 1;
    const int khalf = w & 1;
    // epilogue mapping
    const int be      = tid >> 5;             // 0..15 (batch)
    const int k8      = (tid & 31) * 8;       // 0..248
    const int kk_e    = k8 >> 5;
    const int lane_hm = (be & 15) | (((k8 >> 3) & 3) << 4);

    const uint4* Uw = (const uint4*)U_sw + ((size_t)((g_w * 16 + khalf * 8) * 8)) * 64 + lane;
    float* st = (float*)(smem + ST_OFF);

    // ---- one-time fills ----
    // register-resident frags (kk 0..3)
    uint4 ures[32];
    #pragma unroll
    for (int nt = 0; nt < 8; ++nt)
        #pragma unroll
        for (int kk = 0; kk < 4; ++kk)
            ures[nt * 4 + kk] = Uw[(nt * 8 + kk) * 64];
    // LDS frags (kk==4, nt 0..6)
    #pragma unroll
    for (int f = 0; f < 7; ++f) {
        uint4 v = Uw[(f * 8 + 4) * 64];
        *(uint4*)(smem + ULDS_OFF + w * ULDS_W + f * 1024 + lane * 16) = v;
    }
    // zero hm region (h0 = 0)
    for (int i = tid; i < HM_G_STRIDE * 4 / 16; i += SCAN_THREADS)
        ((uint4*)smem)[i] = make_uint4(0u, 0u, 0u, 0u);

    // persistent epilogue registers
    uint4 zhreg[4];
    float c8[8], h8[8];
    #pragma unroll
    for (int g = 0; g < 4; ++g)
        zhreg[g] = *(const uint4*)(zh + ((size_t)g * B_SZ + (b0 + be)) * H_SZ + k8);
    #pragma unroll
    for (int j = 0; j < 8; ++j) c8[j] = 0.f;

    __syncthreads();

    for (int t = 0; t < T_STEPS; ++t) {
        // ---- MFMA phase ----
        I4S8 afr[8];
        #pragma unroll
        for (int kk = 0; kk < 8; ++kk)
            afr[kk].u = *(const uint4*)(smem + g_w * HM_G_STRIDE + kk * 1040 + lane * 16);

        uint4 sbuf[4];
        #pragma unroll
        for (int q = 0; q < 4; ++q) sbuf[q] = Uw[SFRG[q] * 64];

        #pragma unroll
        for (int p = 0; p < 4; ++p) {
            floatx4 acc[2];
            #pragma unroll
            for (int e = 0; e < 2; ++e)
                #pragma unroll
                for (int r = 0; r < 4; ++r) acc[e][r] = 0.f;

            // LDS frag (kk==4) for each nt of this pair (nt<7)
            uint4 lb[2];
            #pragma unroll
            for (int e = 0; e < 2; ++e) {
                const int nt = 2 * p + e;
                if (nt < 7)
                    lb[e] = *(const uint4*)(smem + ULDS_OFF + w * ULDS_W + nt * 1024 + lane * 16);
            }

            #pragma unroll
            for (int kk = 0; kk < 8; ++kk) {
                #pragma unroll
                for (int e = 0; e < 2; ++e) {
                    const int nt = 2 * p + e;
                    I4S8 bb;
                    if (kk < 4) {
                        bb.u = ures[nt * 4 + kk];
                    } else if (kk == 4 && nt < 7) {
                        bb.u = lb[e];
                    } else {
                        const int o = SORD[nt][kk];
                        bb.u = sbuf[o & 3];
                        if (o + 4 < 25) sbuf[o & 3] = Uw[SFRG[o + 4] * 64];
                    }
                    acc[e] = __builtin_amdgcn_mfma_f32_16x16x32_bf16(afr[kk].s, bb.s, acc[e], 0, 0, 0);
                }
            }
            // write st (fp32, conflict-free pattern)
            #pragma unroll
            for (int e = 0; e < 2; ++e) {
                const int nt = 2 * p + e;
                int kcol  = khalf * 128 + nt * 16 + (lane & 15);
                int brow4 = (lane >> 4) * 4;
                #pragma unroll
                for (int r = 0; r < 4; ++r)
                    st[((brow4 + r) * 4 + g_w) * ST_ROW + kcol] = acc[e][r];
            }
        }
        __syncthreads();

        // ---- epilogue ----
        uint4 xp[4];
        #pragma unroll
        for (int g = 0; g < 4; ++g)
            xp[g] = *(const uint4*)(xpre + (((size_t)t * B_SZ + (b0 + be)) * 4 + g) * H_SZ + k8);

        float sg[4][8];
        #pragma unroll
        for (int g = 0; g < 4; ++g) {
            const float* strow = st + ((be * 4 + g) * ST_ROW + k8);
            float4 lo = *(const float4*)(strow);
            float4 hi = *(const float4*)(strow + 4);
            sg[g][0] = lo.x; sg[g][1] = lo.y; sg[g][2] = lo.z; sg[g][3] = lo.w;
            sg[g][4] = hi.x; sg[g][5] = hi.y; sg[g][6] = hi.z; sg[g][7] = hi.w;
            const ushort* xs = (const ushort*)&xp[g];
            #pragma unroll
            for (int j = 0; j < 8; ++j) sg[g][j] += bf2f(xs[j]);
        }
        #pragma unroll
        for (int j = 0; j < 8; ++j) {
            float iv = fast_sigmoid(sg[0][j]);
            float fv = fast_sigmoid(sg[1][j]);
            float ov = fast_sigmoid(sg[2][j]);
            float gv = fast_tanh(sg[3][j]);
            float c  = fv * c8[j] + iv * gv;
            c8[j] = c;
            h8[j] = ov * fast_tanh(c);
        }
        {
            float* op = out + ((size_t)t * B_SZ + (b0 + be)) * H_SZ + k8;
            *(float4*)(op)     = make_float4(h8[0], h8[1], h8[2], h8[3]);
            *(float4*)(op + 4) = make_float4(h8[4], h8[5], h8[6], h8[7]);
        }
        // hm = h * zh -> LDS A-frag layout
        #pragma unroll
        for (int g = 0; g < 4; ++g) {
            const ushort* zs = (const ushort*)&zhreg[g];
            uint4 pk;
            pk.x = (uint)f2bf(h8[0] * bf2f(zs[0])) | ((uint)f2bf(h8[1] * bf2f(zs[1])) << 16);
            pk.y = (uint)f2bf(h8[2] * bf2f(zs[2])) | ((uint)f2bf(h8[3] * bf2f(zs[3])) << 16);
            pk.z = (uint)f2bf(h8[4] * bf2f(zs[4])) | ((uint)f2bf(h8[5] * bf2f(zs[5])) << 16);
            pk.w = (uint)f2bf(h8[6] * bf2f(zs[6])) | ((uint)f2bf(h8[7] * bf2f(zs[7])) << 16);
            *(uint4*)(smem + g * HM_G_STRIDE + kk_e * 1040 + lane_hm * 16) = pk;
        }
        if (t == T_STEPS - 1) {
            size_t tail = (size_t)T_STEPS * B_SZ * H_SZ;
            float* hp = out + tail + (size_t)(b0 + be) * H_SZ + k8;
            float* cp = hp + (size_t)B_SZ * H_SZ;
            *(float4*)(hp)     = make_float4(h8[0], h8[1], h8[2], h8[3]);
            *(float4*)(hp + 4) = make_float4(h8[4], h8[5], h8[6], h8[7]);
            *(float4*)(cp)     = make_float4(c8[0], c8[1], c8[2], c8[3]);
            *(float4*)(cp + 4) = make_float4(c8[4], c8[5], c8[6], c8[7]);
        }
        __syncthreads();
    }
}

// ---------- launch ----------
extern "C" void kernel_launch(void* const* d_in, const int* in_sizes, int n_in,
                              void* d_out, int out_size, void* d_ws, size_t ws_size,
                              hipStream_t stream) {
    const float* input = (const float*)d_in[0];
    const float* ux    = (const float*)d_in[1];
    const float* uh    = (const float*)d_in[2];
    const float* W     = (const float*)d_in[3];
    const float* Wb    = (const float*)d_in[4];
    const float* U     = (const float*)d_in[5];
    const float* Ub    = (const float*)d_in[6];
    float* out = (float*)d_out;

    // workspace layout (16B aligned)
    float* zx            = (float*)d_ws;                                   // 131072 f32
    __hip_bfloat16* zh   = (__hip_bfloat16*)(zx + 4 * B_SZ * I_SZ);        // 131072 bf16
    __hip_bfloat16* U_sw = zh + 4 * B_SZ * H_SZ;                           // 262144 bf16
    __hip_bfloat16* W_sw = U_sw + 4 * H_SZ * H_SZ;                         // 262144 bf16
    __hip_bfloat16* xpre = W_sw + 4 * H_SZ * I_SZ;                         // T*B*4*H bf16

    mask_kernel<<<dim3(1024), dim3(256), 0, stream>>>(ux, uh, zx, zh);
    uswz_kernel<<<dim3(128), dim3(256), 0, stream>>>(U, U_sw);
    uswz_kernel<<<dim3(128), dim3(256), 0, stream>>>(W, W_sw);

    xpre_mfma_kernel<<<dim3(1024), dim3(512), 0, stream>>>(input, zx, W_sw, Wb, Ub, xpre);

    scan_mfma_kernel<<<dim3(SCAN_BLOCKS), dim3(SCAN_THREADS), SMEM_BYTES, stream>>>(
        xpre, zh, U_sw, out);
}